// Round 1
// baseline (1607.980 us; speedup 1.0000x reference)
//
#include <hip/hip_runtime.h>
#include <hip/hip_bf16.h>
#include <math.h>

#define H 64
#define F 18
#define BSC 96        // destination nodes per bucket (compile-time)
#define NBK_MAX 1152  // max buckets supported by LDS histograms (N <= 110592)
#define EPB 8192      // edges per block in count/place passes

typedef _Float16 f16x8 __attribute__((ext_vector_type(8)));
typedef float f32x4 __attribute__((ext_vector_type(4)));

// ---------------------------------------------------------------- embed ----
__global__ __launch_bounds__(256) void embed_kernel(
    const float* __restrict__ nf, const float* __restrict__ W,
    const float* __restrict__ b, _Float16* __restrict__ xh, int N)
{
    int n = blockIdx.x * 256 + threadIdx.x;
    if (n >= N) return;
    float acc[H];
#pragma unroll
    for (int j = 0; j < H; ++j) acc[j] = b[j];
    const float* f = nf + (long)n * F;
#pragma unroll
    for (int i = 0; i < F; ++i) {
        float c = f[i];
        const float* w = W + i * H;
#pragma unroll
        for (int j = 0; j < H; ++j) acc[j] += c * w[j];
    }
    union { uint4 v[8]; _Float16 h[64]; } O;
#pragma unroll
    for (int j = 0; j < H; ++j) O.h[j] = (_Float16)fmaxf(acc[j], 0.f);
    uint4* xo = (uint4*)(xh + (size_t)n * H);
#pragma unroll
    for (int i = 0; i < 8; ++i) xo[i] = O.v[i];
}

// ------------------------------------------------- B-fragment prepack -----
__global__ __launch_bounds__(256) void packfrag_kernel(
    const float* __restrict__ mW1, const float* __restrict__ aW1,
    f16x8* __restrict__ msgB, f16x8* __restrict__ attB)
{
    int t = blockIdx.x * 256 + threadIdx.x;  // 0..3071
    if (t >= 3072) return;
    int lane = t & 63;
    int frag = t >> 6;            // 0..47
    int l = frag / 24, f = frag % 24;
    int quad = lane >> 4, l15 = lane & 15;
    f16x8 v;
    if (f < 16) {
        int nt = f >> 2, kk = f & 3;
        const float* W = mW1 + (size_t)l * 128 * 64;
#pragma unroll
        for (int j = 0; j < 8; ++j) {
            int k = kk * 32 + quad * 8 + j;
            v[j] = (_Float16)W[k * 64 + nt * 16 + l15];
        }
        msgB[((size_t)l * 16 + f) * 64 + lane] = v;
    } else {
        int f2 = f - 16;
        int nt = f2 >> 2, kk = f2 & 3;
        const float* W = aW1 + (size_t)l * 128 * 32;
#pragma unroll
        for (int j = 0; j < 8; ++j) {
            int k = kk * 32 + quad * 8 + j;
            v[j] = (_Float16)W[k * 32 + nt * 16 + l15];
        }
        attB[((size_t)l * 8 + f2) * 64 + lane] = v;
    }
}

// ---------------------------------------------- update-path precompute ----
__global__ __launch_bounds__(256) void prep_update_kernel(
    const float* __restrict__ mW2, const float* __restrict__ mb2,
    const float* __restrict__ uW1,
    float* __restrict__ M2U, float* __restrict__ mbu)
{
    int t = blockIdx.x * 256 + threadIdx.x;  // 0..8191
    if (t >= 2 * 64 * 64) return;
    int l = t >> 12, r = t & 4095;
    int i = r >> 6, j = r & 63;
    const float* W2 = mW2 + (size_t)l * 4096;
    const float* U1b = uW1 + (size_t)l * 8192 + 4096;  // rows 64..127
    float s = 0.f;
    for (int k = 0; k < 64; ++k) s += W2[i * 64 + k] * U1b[k * 64 + j];
    M2U[t] = s;
    if (i == 0) {
        float sb = 0.f;
        const float* b2 = mb2 + (size_t)l * 64;
        for (int k = 0; k < 64; ++k) sb += b2[k] * U1b[k * 64 + j];
        mbu[l * 64 + j] = sb;
    }
}

// R17: aggN is now stored in TRUE feature order (the fused kernel
// accumulates at feature nt*16+l15 directly), so g==1 is no longer
// row-permuted.
__global__ __launch_bounds__(256) void packfrag_upd_kernel(
    const float* __restrict__ uW1, const float* __restrict__ M2U,
    const float* __restrict__ uW2, f16x8* __restrict__ updB)
{
    int t = blockIdx.x * 256 + threadIdx.x;  // 0..3071
    if (t >= 3072) return;
    int lane = t & 63;
    int frag = t >> 6;  // 0..47
    int l = frag / 24, f = frag % 24;
    int quad = lane >> 4, l15 = lane & 15;
    int g = f >> 3, ff = f & 7;
    int nt = ff >> 1, kk = ff & 1;
    const float* src;
    if (g == 0)      src = uW1 + (size_t)l * 8192;       // rows 0..63
    else if (g == 1) src = M2U + (size_t)l * 4096;
    else             src = uW2 + (size_t)l * 4096;
    f16x8 v;
#pragma unroll
    for (int j = 0; j < 8; ++j) {
        int k = kk * 32 + quad * 8 + j;
        v[j] = (_Float16)src[k * 64 + nt * 16 + l15];
    }
    updB[(size_t)frag * 64 + lane] = v;
}

// ----------------------------------------------- scan (generic, <=256k) ---
__global__ __launch_bounds__(256) void scan1_kernel(
    const int* __restrict__ deg, int* __restrict__ part,
    int* __restrict__ bsum, int N)
{
    __shared__ int lds[256];
    int t = threadIdx.x;
    int base = blockIdx.x * 1024 + t * 4;
    int v[4];
#pragma unroll
    for (int s = 0; s < 4; ++s) v[s] = (base + s < N) ? deg[base + s] : 0;
    int sum = v[0] + v[1] + v[2] + v[3];
    lds[t] = sum;
    __syncthreads();
    for (int off = 1; off < 256; off <<= 1) {
        int xv = (t >= off) ? lds[t - off] : 0;
        __syncthreads();
        lds[t] += xv;
        __syncthreads();
    }
    int excl = lds[t] - sum;
    if (t == 255) bsum[blockIdx.x] = lds[255];
    int p = excl;
#pragma unroll
    for (int s = 0; s < 4; ++s) {
        if (base + s < N) part[base + s] = p;
        p += v[s];
    }
}

__global__ __launch_bounds__(256) void scan2_kernel(int* __restrict__ bsum, int nb)
{
    __shared__ int lds[256];
    int t = threadIdx.x;
    int v = (t < nb) ? bsum[t] : 0;
    lds[t] = v;
    __syncthreads();
    for (int off = 1; off < 256; off <<= 1) {
        int xv = (t >= off) ? lds[t - off] : 0;
        __syncthreads();
        lds[t] += xv;
        __syncthreads();
    }
    if (t < nb) bsum[t] = lds[t] - v;
}

__global__ __launch_bounds__(256) void scan3_kernel(
    int* __restrict__ part, const int* __restrict__ bsum, int N)
{
    int i = blockIdx.x * 256 + threadIdx.x;
    if (i >= N) return;
    part[i] = part[i] + bsum[i >> 10];
}

// ----------------------------------------- coarse bucket partition --------
__global__ __launch_bounds__(256) void count_bucket_kernel(
    const int* __restrict__ col, int* __restrict__ cnt,
    int E, int NB, int NBK)
{
    __shared__ int lc[NBK_MAX];
    int t = threadIdx.x;
    for (int i = t; i < NBK; i += 256) lc[i] = 0;
    __syncthreads();
#pragma unroll
    for (int s = 0; s < EPB / 256; ++s) {
        int e = blockIdx.x * EPB + s * 256 + t;
        if (e < E) atomicAdd(lc + (unsigned)col[e] / BSC, 1);
    }
    __syncthreads();
    for (int i = t; i < NBK; i += 256)
        cnt[(size_t)i * NB + blockIdx.x] = lc[i];
}

__global__ __launch_bounds__(256) void place_kernel(
    const int* __restrict__ row, const int* __restrict__ col,
    const float* __restrict__ ew, const int* __restrict__ off,
    int4* __restrict__ edata, int E, int NB, int NBK)
{
    __shared__ int lc[NBK_MAX];
    int t = threadIdx.x;
    for (int i = t; i < NBK; i += 256) lc[i] = 0;
    __syncthreads();
#pragma unroll
    for (int s = 0; s < EPB / 256; ++s) {
        int e = blockIdx.x * EPB + s * 256 + t;
        if (e < E) {
            int cv = col[e];
            int c = (unsigned)cv / BSC;
            int r = atomicAdd(lc + c, 1);
            int pos = off[(size_t)c * NB + blockIdx.x] + r;
            edata[pos] = make_int4(row[e], cv, __float_as_int(ew[e]), 0);
        }
    }
}

// ---------------------------------------------------------- fused edge ----
// R17: one block owns one bucket of BSC destination nodes. The MFMA
// attention+message pipeline is identical to R16's edge_mfma, but the
// epilogue accumulates relu(msg)*fw into an LDS fp32 accumulator via
// ds_add_f32 (unsafeAtomicAdd) instead of streaming a 207 MB bf16
// intermediate to HBM. Bucket sums are complete at block end (place
// guarantees all edges of a node land in its bucket), so the block
// finalizes normalization and writes aggN = agg/norm (f16) + snorm.
// +1-row pad on acc: bank = (nl + feat) % 32 -> ~2-way (free, m136).
__global__ __launch_bounds__(256) void edge_fused_kernel(
    const _Float16* __restrict__ xh,
    const int4* __restrict__ edata, const int* __restrict__ off,
    const f16x8* __restrict__ msgB,  // [16][64] this layer
    const f16x8* __restrict__ attB,  // [8][64]
    const float* __restrict__ b1, const float* __restrict__ ab1,
    const float* __restrict__ aW2, const float* __restrict__ ab2,
    _Float16* __restrict__ aggN, float* __restrict__ snorm,
    int N, int E, int NB, int NBK)
{
    __shared__ float acc[BSC][H + 1];   // +1 pad: spread LDS banks
    __shared__ float fwa[BSC];
    int tid = threadIdx.x;
    int b = blockIdx.x;
    for (int i = tid; i < BSC * (H + 1); i += 256) ((float*)acc)[i] = 0.f;
    for (int i = tid; i < BSC; i += 256) fwa[i] = 0.f;

    int base = off[(size_t)b * NB];
    int end  = (b + 1 < NBK) ? off[(size_t)(b + 1) * NB] : E;
    int ecnt = end - base;
    int nlo  = b * BSC;

    int wib = tid >> 6;
    int lane = tid & 63;
    int quad = lane >> 4, l15 = lane & 15;

    f16x8 mb[4][4], ab[2][4];
#pragma unroll
    for (int nt = 0; nt < 4; ++nt)
#pragma unroll
        for (int kk = 0; kk < 4; ++kk)
            mb[nt][kk] = msgB[(nt * 4 + kk) * 64 + lane];
#pragma unroll
    for (int nt = 0; nt < 2; ++nt)
#pragma unroll
        for (int kk = 0; kk < 4; ++kk)
            ab[nt][kk] = attB[(nt * 4 + kk) * 64 + lane];

    float ab1v0 = ab1[l15], ab1v1 = ab1[16 + l15];
    float aw20 = aW2[l15], aw21 = aW2[16 + l15];
    float ab2v = ab2[0];
    float bm[4];
#pragma unroll
    for (int nt = 0; nt < 4; ++nt) bm[nt] = b1[nt * 16 + l15];

    int jsw = ((l15 & 3) << 2) | (l15 >> 2);   // 4x4 transpose of l15
    __syncthreads();   // LDS zero done before any atomics

    int ntiles = (ecnt + 63) >> 6;
    for (int t = wib; t < ntiles; t += 4) {
        int wbase = t << 6;
        int eown = wbase + lane;
        int4 edmy = edata[base + (eown < ecnt ? eown : ecnt - 1)];

        // ---- prologue: load A for sub-tile 0 ----
        f16x8 Acur[4], Anxt[4];
        {
            int sA = jsw;
            int rowv = __shfl(edmy.x, sA);
            int colv = __shfl(edmy.y, sA);
            const f16x8* rowp = (const f16x8*)(xh + (size_t)rowv * H);
            const f16x8* colp = (const f16x8*)(xh + (size_t)colv * H);
            Acur[0] = rowp[quad];
            Acur[1] = rowp[4 + quad];
            Acur[2] = colp[quad];
            Acur[3] = colp[4 + quad];
        }

#pragma unroll
        for (int mt = 0; mt < 4; ++mt) {
            // ---- issue next sub-tile's loads first (overlap) ----
            if (mt < 3) {
                int sA = (mt + 1) * 16 + jsw;
                int rowv = __shfl(edmy.x, sA);
                int colv = __shfl(edmy.y, sA);
                const f16x8* rowp = (const f16x8*)(xh + (size_t)rowv * H);
                const f16x8* colp = (const f16x8*)(xh + (size_t)colv * H);
                Anxt[0] = rowp[quad];
                Anxt[1] = rowp[4 + quad];
                Anxt[2] = colp[quad];
                Anxt[3] = colp[4 + quad];
            }

            // ---- attention GEMM (bias in C-init) ----
            f32x4 ac0 = {ab1v0, ab1v0, ab1v0, ab1v0};
            f32x4 ac1 = {ab1v1, ab1v1, ab1v1, ab1v1};
#pragma unroll
            for (int kk = 0; kk < 4; ++kk) {
                ac0 = __builtin_amdgcn_mfma_f32_16x16x32_f16(Acur[kk], ab[0][kk], ac0, 0, 0, 0);
                ac1 = __builtin_amdgcn_mfma_f32_16x16x32_f16(Acur[kk], ab[1][kk], ac1, 0, 0, 0);
            }
            float p[4];
#pragma unroll
            for (int r = 0; r < 4; ++r)
                p[r] = fmaxf(ac0[r], 0.f) * aw20 + fmaxf(ac1[r], 0.f) * aw21;
#pragma unroll
            for (int o = 1; o < 16; o <<= 1) {
#pragma unroll
                for (int r = 0; r < 4; ++r) p[r] += __shfl_xor(p[r], o);
            }
            float fw[4];
#pragma unroll
            for (int r = 0; r < 4; ++r) {
                int sl = mt * 16 + r * 4 + quad;
                float ewv = (wbase + sl < ecnt)
                            ? __int_as_float(__shfl(edmy.z, sl)) : 0.f;
                fw[r] = ewv / (1.f + __expf(-(p[r] + ab2v)));
            }

            // ---- message GEMM (bias in C-init) ----
            f32x4 mc[4];
#pragma unroll
            for (int nt = 0; nt < 4; ++nt) {
                f32x4 cc = {bm[nt], bm[nt], bm[nt], bm[nt]};
#pragma unroll
                for (int kk = 0; kk < 4; ++kk)
                    cc = __builtin_amdgcn_mfma_f32_16x16x32_f16(Acur[kk], mb[nt][kk], cc, 0, 0, 0);
                mc[nt] = cc;
            }

            // ---- epilogue: LDS fp32 segment-accumulate ----
#pragma unroll
            for (int r = 0; r < 4; ++r) {
                int sl = mt * 16 + r * 4 + quad;
                int nl = __shfl(edmy.y, sl) - nlo;   // shfl outside branch
                if (wbase + sl < ecnt) {
                    float* ap = &acc[nl][l15];
#pragma unroll
                    for (int nt = 0; nt < 4; ++nt)
                        unsafeAtomicAdd(ap + nt * 16,
                                        fmaxf(mc[nt][r], 0.f) * fw[r]);
                    if (l15 == 0) unsafeAtomicAdd(&fwa[nl], fw[r]);
                }
            }

            if (mt < 3) {
#pragma unroll
                for (int i = 0; i < 4; ++i) Acur[i] = Anxt[i];
            }
        }
    }

    __syncthreads();
    // ---- finalize: normalize and write aggN (f16) + snorm ----
    int nmax = N - nlo; if (nmax > BSC) nmax = BSC;
    for (int i = wib; i < nmax; i += 4) {
        float fws = fwa[i];
        float inv = 1.f / fmaxf(fws, 1e-6f);
        aggN[(size_t)(nlo + i) * H + lane] = (_Float16)(acc[i][lane] * inv);
        if (lane == 0) snorm[nlo + i] = fws * inv;
    }
}

// --------------------------------------------------------------- update ----
__global__ __launch_bounds__(256, 2) void update_mfma_kernel(
    _Float16* __restrict__ xh, const _Float16* __restrict__ agg,
    const float* __restrict__ snorm,
    const f16x8* __restrict__ Bfrag,  // [24][64] this layer
    const float* __restrict__ mbu,    // [64]
    const float* __restrict__ ub1, const float* __restrict__ ub2, int N)
{
    __shared__ __align__(16) _Float16 hlds[4][16 * 80];
    int wib = threadIdx.x >> 6;
    int lane = threadIdx.x & 63;
    int wid = (blockIdx.x * 256 + threadIdx.x) >> 6;
    int quad = lane >> 4, l15 = lane & 15;
    int nbase = wid * 64;
    if (nbase >= N) return;

    f16x8 Bu[8], Bm[8], Bw[8];
#pragma unroll
    for (int i = 0; i < 8; ++i) {
        Bu[i] = Bfrag[i * 64 + lane];
        Bm[i] = Bfrag[(8 + i) * 64 + lane];
        Bw[i] = Bfrag[(16 + i) * 64 + lane];
    }
    float mbuv[4], b1v[4], b2v[4];
#pragma unroll
    for (int nt = 0; nt < 4; ++nt) {
        mbuv[nt] = mbu[nt * 16 + l15];
        b1v[nt] = ub1[nt * 16 + l15];
        b2v[nt] = ub2[nt * 16 + l15];
    }

    for (int mt = 0; mt < 4; ++mt) {
        int na = nbase + mt * 16 + l15;
        if (na >= N) na = N - 1;
        const f16x8* xrow = (const f16x8*)(xh + (size_t)na * H);
        f16x8 Ax[2];
        Ax[0] = xrow[quad];
        Ax[1] = xrow[4 + quad];
        const f16x8* arow = (const f16x8*)(agg + (size_t)na * H);
        f16x8 Aa[2];
        Aa[0] = arow[quad];
        Aa[1] = arow[4 + quad];

        f32x4 Cx[4], Ca[4];
#pragma unroll
        for (int nt = 0; nt < 4; ++nt) {
            f32x4 cx = {0.f, 0.f, 0.f, 0.f}, ca = {0.f, 0.f, 0.f, 0.f};
#pragma unroll
            for (int kk = 0; kk < 2; ++kk) {
                cx = __builtin_amdgcn_mfma_f32_16x16x32_f16(Ax[kk], Bu[nt * 2 + kk], cx, 0, 0, 0);
                ca = __builtin_amdgcn_mfma_f32_16x16x32_f16(Aa[kk], Bm[nt * 2 + kk], ca, 0, 0, 0);
            }
            Cx[nt] = cx; Ca[nt] = ca;
        }

        int noder = nbase + mt * 16 + quad * 4;
        float sn_r[4];
#pragma unroll
        for (int r = 0; r < 4; ++r) {
            int ng = noder + r; if (ng >= N) ng = N - 1;
            sn_r[r] = snorm[ng];
        }

#pragma unroll
        for (int nt = 0; nt < 4; ++nt) {
#pragma unroll
            for (int r = 0; r < 4; ++r) {
                float hv = fmaxf(Cx[nt][r] + Ca[nt][r]
                                 + sn_r[r] * mbuv[nt] + b1v[nt], 0.f);
                hlds[wib][(quad * 4 + r) * 80 + nt * 16 + l15] = (_Float16)hv;
            }
        }
        __asm__ __volatile__("s_waitcnt lgkmcnt(0)" ::: "memory");
        f16x8 Ah[2];
        Ah[0] = *(const f16x8*)&hlds[wib][l15 * 80 + quad * 8];
        Ah[1] = *(const f16x8*)&hlds[wib][l15 * 80 + 32 + quad * 8];
        __asm__ __volatile__("s_waitcnt lgkmcnt(0)" ::: "memory");

        f32x4 C2[4];
#pragma unroll
        for (int nt = 0; nt < 4; ++nt) {
            f32x4 cc = {0.f, 0.f, 0.f, 0.f};
#pragma unroll
            for (int kk = 0; kk < 2; ++kk)
                cc = __builtin_amdgcn_mfma_f32_16x16x32_f16(Ah[kk], Bw[nt * 2 + kk], cc, 0, 0, 0);
            C2[nt] = cc;
        }

#pragma unroll
        for (int r = 0; r < 4; ++r) {
            int ng = noder + r;
            if (ng < N) {
#pragma unroll
                for (int nt = 0; nt < 4; ++nt) {
                    size_t idx = (size_t)ng * H + nt * 16 + l15;
                    float xo = (float)xh[idx];
                    xh[idx] = (_Float16)fmaxf(C2[nt][r] + b2v[nt] + xo, 0.f);
                }
            }
        }
    }
}

// ----------------------------------------------------------------- head ----
__global__ __launch_bounds__(256) void max_kernel(
    const _Float16* __restrict__ xh16, unsigned int* __restrict__ serp, int N)
{
    int j = threadIdx.x & (H - 1);
    int g = (blockIdx.x * 256 + threadIdx.x) >> 6;
    int stride = (gridDim.x * 256) >> 6;
    float m = 0.f;  // x >= 0 after relu
    for (int n = g; n < N; n += stride)
        m = fmaxf(m, (float)xh16[(size_t)n * H + j]);
    atomicMax(serp + j, __float_as_uint(m));
}

__global__ void head_kernel(const unsigned int* __restrict__ serp,
                            const float* __restrict__ hW,
                            const float* __restrict__ hb,
                            float* __restrict__ out)
{
    int j = threadIdx.x;  // 64 threads = 1 wave
    float v = __uint_as_float(serp[j]) * hW[j];
#pragma unroll
    for (int off = 32; off > 0; off >>= 1) v += __shfl_down(v, off);
    if (j == 0) out[0] = v + hb[0];
}

// --------------------------------------------------------------- launch ----
extern "C" void kernel_launch(void* const* d_in, const int* in_sizes, int n_in,
                              void* d_out, int out_size, void* d_ws, size_t ws_size,
                              hipStream_t stream)
{
    const float* nf  = (const float*)d_in[0];
    const int*   ei  = (const int*)d_in[1];
    const float* ew  = (const float*)d_in[2];
    const float* eW  = (const float*)d_in[3];
    const float* eb_ = (const float*)d_in[4];
    const float* mW1 = (const float*)d_in[5];
    const float* mb1 = (const float*)d_in[6];
    const float* mW2 = (const float*)d_in[7];
    const float* mb2 = (const float*)d_in[8];
    const float* aW1 = (const float*)d_in[9];
    const float* ab1 = (const float*)d_in[10];
    const float* aW2 = (const float*)d_in[11];
    const float* ab2 = (const float*)d_in[12];
    const float* uW1 = (const float*)d_in[13];
    const float* ub1 = (const float*)d_in[14];
    const float* uW2 = (const float*)d_in[15];
    const float* ub2 = (const float*)d_in[16];
    const float* hW  = (const float*)d_in[17];
    const float* hb  = (const float*)d_in[18];

    int N = in_sizes[0] / F;
    int E = in_sizes[2];
    const int* row = ei;
    const int* col = ei + E;

    size_t Nr = ((size_t)N + 3) & ~(size_t)3;
    size_t Er = ((size_t)E + 3) & ~(size_t)3;
    int NBK = (N + BSC - 1) / BSC;         // buckets (= fused-kernel grid)
    int NB  = (E + EPB - 1) / EPB;         // blocks in count/place passes
    size_t M = (size_t)NBK * NB;           // bucket-count array size
    size_t Mr = (M + 3) & ~(size_t)3;

    _Float16* xh   = (_Float16*)d_ws;                 // Nr*64 f16
    _Float16* aggN = xh + Nr * 64;                    // Nr*64 f16 (normalized)
    float* snorm   = (float*)(aggN + Nr * 64);        // Nr
    unsigned int* serp = (unsigned int*)(snorm + Nr); // 64
    int* bsum      = (int*)(serp + 64);               // 256
    f16x8* msgB    = (f16x8*)(bsum + 256);            // 2048 units
    f16x8* attB    = msgB + 2048;                     // 1024 units
    float* M2U     = (float*)(attB + 1024);           // 8192
    float* mbu     = M2U + 8192;                      // 128
    f16x8* updB    = (f16x8*)(mbu + 128);             // 3072 units
    int* cnt       = (int*)(updB + 3072);             // Mr
    int* off       = cnt + Mr;                        // Mr
    int4* edata    = (int4*)(off + Mr);               // Er int4

    int nb_n = (N + 255) / 256;
    int nb_scanM = (int)((M + 1023) / 1024);          // <=256 (M<=262144)

    count_bucket_kernel<<<NB, 256, 0, stream>>>(col, cnt, E, NB, NBK);
    scan1_kernel<<<nb_scanM, 256, 0, stream>>>(cnt, off, bsum, (int)M);
    scan2_kernel<<<1, 256, 0, stream>>>(bsum, nb_scanM);
    scan3_kernel<<<(int)((M + 255) / 256), 256, 0, stream>>>(off, bsum, (int)M);
    place_kernel<<<NB, 256, 0, stream>>>(row, col, ew, off, edata, E, NB, NBK);

    packfrag_kernel<<<12, 256, 0, stream>>>(mW1, aW1, msgB, attB);
    prep_update_kernel<<<32, 256, 0, stream>>>(mW2, mb2, uW1, M2U, mbu);
    packfrag_upd_kernel<<<12, 256, 0, stream>>>(uW1, M2U, uW2, updB);
    embed_kernel<<<nb_n, 256, 0, stream>>>(nf, eW, eb_, xh, N);

    int nwaves_n = (N + 63) / 64;
    for (int l = 0; l < 2; ++l) {
        edge_fused_kernel<<<NBK, 256, 0, stream>>>(
            xh, edata, off,
            msgB + (size_t)l * 16 * 64,
            attB + (size_t)l * 8 * 64,
            mb1 + (size_t)l * H,
            ab1 + (size_t)l * (H / 2),
            aW2 + (size_t)l * (H / 2), ab2 + (size_t)l,
            aggN, snorm, N, E, NB, NBK);
        update_mfma_kernel<<<(nwaves_n + 3) / 4, 256, 0, stream>>>(
            xh, aggN, snorm,
            updB + (size_t)l * 24 * 64,
            mbu + (size_t)l * 64,
            ub1 + (size_t)l * H, ub2 + (size_t)l * H, N);
    }

    hipMemsetAsync(serp, 0, 64 * sizeof(unsigned int), stream);
    max_kernel<<<256, 256, 0, stream>>>(xh, serp, N);
    head_kernel<<<1, 64, 0, stream>>>(serp, hW, hb, (float*)d_out);
}

// Round 2
// 1607.208 us; speedup vs baseline: 1.0005x; 1.0005x over previous
//
#include <hip/hip_runtime.h>
#include <hip/hip_bf16.h>
#include <math.h>

#define H 64
#define F 18
#define BSC 96        // destination nodes per bucket (compile-time)
#define NBK_MAX 1152  // max buckets supported by LDS histograms (N <= 110592)
#define EPB 8192      // edges per block in count/place passes

typedef _Float16 f16x8 __attribute__((ext_vector_type(8)));
typedef float f32x4 __attribute__((ext_vector_type(4)));

// ---------------------------------------------------------------- embed ----
__global__ __launch_bounds__(256) void embed_kernel(
    const float* __restrict__ nf, const float* __restrict__ W,
    const float* __restrict__ b, _Float16* __restrict__ xh, int N)
{
    int n = blockIdx.x * 256 + threadIdx.x;
    if (n >= N) return;
    float acc[H];
#pragma unroll
    for (int j = 0; j < H; ++j) acc[j] = b[j];
    const float* f = nf + (long)n * F;
#pragma unroll
    for (int i = 0; i < F; ++i) {
        float c = f[i];
        const float* w = W + i * H;
#pragma unroll
        for (int j = 0; j < H; ++j) acc[j] += c * w[j];
    }
    union { uint4 v[8]; _Float16 h[64]; } O;
#pragma unroll
    for (int j = 0; j < H; ++j) O.h[j] = (_Float16)fmaxf(acc[j], 0.f);
    uint4* xo = (uint4*)(xh + (size_t)n * H);
#pragma unroll
    for (int i = 0; i < 8; ++i) xo[i] = O.v[i];
}

// ------------------------------------------------- B-fragment prepack -----
__global__ __launch_bounds__(256) void packfrag_kernel(
    const float* __restrict__ mW1, const float* __restrict__ aW1,
    f16x8* __restrict__ msgB, f16x8* __restrict__ attB)
{
    int t = blockIdx.x * 256 + threadIdx.x;  // 0..3071
    if (t >= 3072) return;
    int lane = t & 63;
    int frag = t >> 6;            // 0..47
    int l = frag / 24, f = frag % 24;
    int quad = lane >> 4, l15 = lane & 15;
    f16x8 v;
    if (f < 16) {
        int nt = f >> 2, kk = f & 3;
        const float* W = mW1 + (size_t)l * 128 * 64;
#pragma unroll
        for (int j = 0; j < 8; ++j) {
            int k = kk * 32 + quad * 8 + j;
            v[j] = (_Float16)W[k * 64 + nt * 16 + l15];
        }
        msgB[((size_t)l * 16 + f) * 64 + lane] = v;
    } else {
        int f2 = f - 16;
        int nt = f2 >> 2, kk = f2 & 3;
        const float* W = aW1 + (size_t)l * 128 * 32;
#pragma unroll
        for (int j = 0; j < 8; ++j) {
            int k = kk * 32 + quad * 8 + j;
            v[j] = (_Float16)W[k * 32 + nt * 16 + l15];
        }
        attB[((size_t)l * 8 + f2) * 64 + lane] = v;
    }
}

// ---------------------------------------------- update-path precompute ----
__global__ __launch_bounds__(256) void prep_update_kernel(
    const float* __restrict__ mW2, const float* __restrict__ mb2,
    const float* __restrict__ uW1,
    float* __restrict__ M2U, float* __restrict__ mbu)
{
    int t = blockIdx.x * 256 + threadIdx.x;  // 0..8191
    if (t >= 2 * 64 * 64) return;
    int l = t >> 12, r = t & 4095;
    int i = r >> 6, j = r & 63;
    const float* W2 = mW2 + (size_t)l * 4096;
    const float* U1b = uW1 + (size_t)l * 8192 + 4096;  // rows 64..127
    float s = 0.f;
    for (int k = 0; k < 64; ++k) s += W2[i * 64 + k] * U1b[k * 64 + j];
    M2U[t] = s;
    if (i == 0) {
        float sb = 0.f;
        const float* b2 = mb2 + (size_t)l * 64;
        for (int k = 0; k < 64; ++k) sb += b2[k] * U1b[k * 64 + j];
        mbu[l * 64 + j] = sb;
    }
}

// aggN stored in TRUE feature order; g==1 no longer row-permuted.
__global__ __launch_bounds__(256) void packfrag_upd_kernel(
    const float* __restrict__ uW1, const float* __restrict__ M2U,
    const float* __restrict__ uW2, f16x8* __restrict__ updB)
{
    int t = blockIdx.x * 256 + threadIdx.x;  // 0..3071
    if (t >= 3072) return;
    int lane = t & 63;
    int frag = t >> 6;  // 0..47
    int l = frag / 24, f = frag % 24;
    int quad = lane >> 4, l15 = lane & 15;
    int g = f >> 3, ff = f & 7;
    int nt = ff >> 1, kk = ff & 1;
    const float* src;
    if (g == 0)      src = uW1 + (size_t)l * 8192;       // rows 0..63
    else if (g == 1) src = M2U + (size_t)l * 4096;
    else             src = uW2 + (size_t)l * 4096;
    f16x8 v;
#pragma unroll
    for (int j = 0; j < 8; ++j) {
        int k = kk * 32 + quad * 8 + j;
        v[j] = (_Float16)src[k * 64 + nt * 16 + l15];
    }
    updB[(size_t)frag * 64 + lane] = v;
}

// ----------------------------------------------- scan (generic, <=256k) ---
__global__ __launch_bounds__(256) void scan1_kernel(
    const int* __restrict__ deg, int* __restrict__ part,
    int* __restrict__ bsum, int N)
{
    __shared__ int lds[256];
    int t = threadIdx.x;
    int base = blockIdx.x * 1024 + t * 4;
    int v[4];
#pragma unroll
    for (int s = 0; s < 4; ++s) v[s] = (base + s < N) ? deg[base + s] : 0;
    int sum = v[0] + v[1] + v[2] + v[3];
    lds[t] = sum;
    __syncthreads();
    for (int off = 1; off < 256; off <<= 1) {
        int xv = (t >= off) ? lds[t - off] : 0;
        __syncthreads();
        lds[t] += xv;
        __syncthreads();
    }
    int excl = lds[t] - sum;
    if (t == 255) bsum[blockIdx.x] = lds[255];
    int p = excl;
#pragma unroll
    for (int s = 0; s < 4; ++s) {
        if (base + s < N) part[base + s] = p;
        p += v[s];
    }
}

__global__ __launch_bounds__(256) void scan2_kernel(int* __restrict__ bsum, int nb)
{
    __shared__ int lds[256];
    int t = threadIdx.x;
    int v = (t < nb) ? bsum[t] : 0;
    lds[t] = v;
    __syncthreads();
    for (int off = 1; off < 256; off <<= 1) {
        int xv = (t >= off) ? lds[t - off] : 0;
        __syncthreads();
        lds[t] += xv;
        __syncthreads();
    }
    if (t < nb) bsum[t] = lds[t] - v;
}

__global__ __launch_bounds__(256) void scan3_kernel(
    int* __restrict__ part, const int* __restrict__ bsum, int N)
{
    int i = blockIdx.x * 256 + threadIdx.x;
    if (i >= N) return;
    part[i] = part[i] + bsum[i >> 10];
}

// ----------------------------------------- coarse bucket partition --------
__global__ __launch_bounds__(256) void count_bucket_kernel(
    const int* __restrict__ col, int* __restrict__ cnt,
    int E, int NB, int NBK)
{
    __shared__ int lc[NBK_MAX];
    int t = threadIdx.x;
    for (int i = t; i < NBK; i += 256) lc[i] = 0;
    __syncthreads();
#pragma unroll
    for (int s = 0; s < EPB / 256; ++s) {
        int e = blockIdx.x * EPB + s * 256 + t;
        if (e < E) atomicAdd(lc + (unsigned)col[e] / BSC, 1);
    }
    __syncthreads();
    for (int i = t; i < NBK; i += 256)
        cnt[(size_t)i * NB + blockIdx.x] = lc[i];
}

__global__ __launch_bounds__(256) void place_kernel(
    const int* __restrict__ row, const int* __restrict__ col,
    const float* __restrict__ ew, const int* __restrict__ off,
    int4* __restrict__ edata, int E, int NB, int NBK)
{
    __shared__ int lc[NBK_MAX];
    int t = threadIdx.x;
    for (int i = t; i < NBK; i += 256) lc[i] = 0;
    __syncthreads();
#pragma unroll
    for (int s = 0; s < EPB / 256; ++s) {
        int e = blockIdx.x * EPB + s * 256 + t;
        if (e < E) {
            int cv = col[e];
            int c = (unsigned)cv / BSC;
            int r = atomicAdd(lc + c, 1);
            int pos = off[(size_t)c * NB + blockIdx.x] + r;
            edata[pos] = make_int4(row[e], cv, __float_as_int(ew[e]), 0);
        }
    }
}

// ---------------------------------------------------------- fused edge ----
// R18: same as R17 but the LDS segment-accumulate uses plain atomicAdd
// indexed DIRECTLY on the __shared__ arrays, so clang's address-space
// inference emits native ds_add_f32 (unsafeAtomicAdd on a generic pointer
// lowered to a flat atomic / per-op-waitcnt sequence: ~200cy x 80/tile
// = the whole R17 regression). Plus cross-tile edata prefetch: tile t+4's
// edata load issues during tile t's compute (one exposed HBM latency per
// tile otherwise, now hidden).
__global__ __launch_bounds__(256) void edge_fused_kernel(
    const _Float16* __restrict__ xh,
    const int4* __restrict__ edata, const int* __restrict__ off,
    const f16x8* __restrict__ msgB,  // [16][64] this layer
    const f16x8* __restrict__ attB,  // [8][64]
    const float* __restrict__ b1, const float* __restrict__ ab1,
    const float* __restrict__ aW2, const float* __restrict__ ab2,
    _Float16* __restrict__ aggN, float* __restrict__ snorm,
    int N, int E, int NB, int NBK)
{
    __shared__ float acc[BSC][H + 1];   // +1 pad: spread LDS banks
    __shared__ float fwa[BSC];
    int tid = threadIdx.x;
    int b = blockIdx.x;
    for (int i = tid; i < BSC * (H + 1); i += 256) ((float*)acc)[i] = 0.f;
    for (int i = tid; i < BSC; i += 256) fwa[i] = 0.f;

    int base = off[(size_t)b * NB];
    int end  = (b + 1 < NBK) ? off[(size_t)(b + 1) * NB] : E;
    int ecnt = end - base;
    int nlo  = b * BSC;

    int wib = tid >> 6;
    int lane = tid & 63;
    int quad = lane >> 4, l15 = lane & 15;

    f16x8 mb[4][4], ab[2][4];
#pragma unroll
    for (int nt = 0; nt < 4; ++nt)
#pragma unroll
        for (int kk = 0; kk < 4; ++kk)
            mb[nt][kk] = msgB[(nt * 4 + kk) * 64 + lane];
#pragma unroll
    for (int nt = 0; nt < 2; ++nt)
#pragma unroll
        for (int kk = 0; kk < 4; ++kk)
            ab[nt][kk] = attB[(nt * 4 + kk) * 64 + lane];

    float ab1v0 = ab1[l15], ab1v1 = ab1[16 + l15];
    float aw20 = aW2[l15], aw21 = aW2[16 + l15];
    float ab2v = ab2[0];
    float bm[4];
#pragma unroll
    for (int nt = 0; nt < 4; ++nt) bm[nt] = b1[nt * 16 + l15];

    int jsw = ((l15 & 3) << 2) | (l15 >> 2);   // 4x4 transpose of l15
    __syncthreads();   // LDS zero done before any atomics

    int ntiles = (ecnt + 63) >> 6;

    // prefetch first tile's edata
    int4 edmy;
    if (wib < ntiles) {
        int eown = (wib << 6) + lane;
        edmy = edata[base + (eown < ecnt ? eown : ecnt - 1)];
    }

    for (int t = wib; t < ntiles; t += 4) {
        int wbase = t << 6;

        // ---- issue NEXT tile's edata load (hidden under this tile) ----
        int4 ednx;
        int tn = t + 4;
        if (tn < ntiles) {
            int eo = (tn << 6) + lane;
            ednx = edata[base + (eo < ecnt ? eo : ecnt - 1)];
        }

        // ---- prologue: load A for sub-tile 0 ----
        f16x8 Acur[4], Anxt[4];
        {
            int sA = jsw;
            int rowv = __shfl(edmy.x, sA);
            int colv = __shfl(edmy.y, sA);
            const f16x8* rowp = (const f16x8*)(xh + (size_t)rowv * H);
            const f16x8* colp = (const f16x8*)(xh + (size_t)colv * H);
            Acur[0] = rowp[quad];
            Acur[1] = rowp[4 + quad];
            Acur[2] = colp[quad];
            Acur[3] = colp[4 + quad];
        }

#pragma unroll
        for (int mt = 0; mt < 4; ++mt) {
            // ---- issue next sub-tile's loads first (overlap) ----
            if (mt < 3) {
                int sA = (mt + 1) * 16 + jsw;
                int rowv = __shfl(edmy.x, sA);
                int colv = __shfl(edmy.y, sA);
                const f16x8* rowp = (const f16x8*)(xh + (size_t)rowv * H);
                const f16x8* colp = (const f16x8*)(xh + (size_t)colv * H);
                Anxt[0] = rowp[quad];
                Anxt[1] = rowp[4 + quad];
                Anxt[2] = colp[quad];
                Anxt[3] = colp[4 + quad];
            }

            // ---- attention GEMM (bias in C-init) ----
            f32x4 ac0 = {ab1v0, ab1v0, ab1v0, ab1v0};
            f32x4 ac1 = {ab1v1, ab1v1, ab1v1, ab1v1};
#pragma unroll
            for (int kk = 0; kk < 4; ++kk) {
                ac0 = __builtin_amdgcn_mfma_f32_16x16x32_f16(Acur[kk], ab[0][kk], ac0, 0, 0, 0);
                ac1 = __builtin_amdgcn_mfma_f32_16x16x32_f16(Acur[kk], ab[1][kk], ac1, 0, 0, 0);
            }
            float p[4];
#pragma unroll
            for (int r = 0; r < 4; ++r)
                p[r] = fmaxf(ac0[r], 0.f) * aw20 + fmaxf(ac1[r], 0.f) * aw21;
#pragma unroll
            for (int o = 1; o < 16; o <<= 1) {
#pragma unroll
                for (int r = 0; r < 4; ++r) p[r] += __shfl_xor(p[r], o);
            }
            float fw[4];
#pragma unroll
            for (int r = 0; r < 4; ++r) {
                int sl = mt * 16 + r * 4 + quad;
                float ewv = (wbase + sl < ecnt)
                            ? __int_as_float(__shfl(edmy.z, sl)) : 0.f;
                fw[r] = ewv / (1.f + __expf(-(p[r] + ab2v)));
            }

            // ---- message GEMM (bias in C-init) ----
            f32x4 mc[4];
#pragma unroll
            for (int nt = 0; nt < 4; ++nt) {
                f32x4 cc = {bm[nt], bm[nt], bm[nt], bm[nt]};
#pragma unroll
                for (int kk = 0; kk < 4; ++kk)
                    cc = __builtin_amdgcn_mfma_f32_16x16x32_f16(Acur[kk], mb[nt][kk], cc, 0, 0, 0);
                mc[nt] = cc;
            }

            // ---- epilogue: LDS fp32 segment-accumulate (ds_add_f32) ----
#pragma unroll
            for (int r = 0; r < 4; ++r) {
                int sl = mt * 16 + r * 4 + quad;
                int nl = __shfl(edmy.y, sl) - nlo;   // shfl outside branch
                if (wbase + sl < ecnt) {
                    float s = fw[r];
                    atomicAdd(&acc[nl][l15],      fmaxf(mc[0][r], 0.f) * s);
                    atomicAdd(&acc[nl][l15 + 16], fmaxf(mc[1][r], 0.f) * s);
                    atomicAdd(&acc[nl][l15 + 32], fmaxf(mc[2][r], 0.f) * s);
                    atomicAdd(&acc[nl][l15 + 48], fmaxf(mc[3][r], 0.f) * s);
                    if (l15 == 0) atomicAdd(&fwa[nl], s);
                }
            }

            if (mt < 3) {
#pragma unroll
                for (int i = 0; i < 4; ++i) Acur[i] = Anxt[i];
            }
        }

        if (tn < ntiles) edmy = ednx;
    }

    __syncthreads();
    // ---- finalize: normalize and write aggN (f16) + snorm ----
    int nmax = N - nlo; if (nmax > BSC) nmax = BSC;
    for (int i = wib; i < nmax; i += 4) {
        float fws = fwa[i];
        float inv = 1.f / fmaxf(fws, 1e-6f);
        aggN[(size_t)(nlo + i) * H + lane] = (_Float16)(acc[i][lane] * inv);
        if (lane == 0) snorm[nlo + i] = fws * inv;
    }
}

// --------------------------------------------------------------- update ----
__global__ __launch_bounds__(256, 2) void update_mfma_kernel(
    _Float16* __restrict__ xh, const _Float16* __restrict__ agg,
    const float* __restrict__ snorm,
    const f16x8* __restrict__ Bfrag,  // [24][64] this layer
    const float* __restrict__ mbu,    // [64]
    const float* __restrict__ ub1, const float* __restrict__ ub2, int N)
{
    __shared__ __align__(16) _Float16 hlds[4][16 * 80];
    int wib = threadIdx.x >> 6;
    int lane = threadIdx.x & 63;
    int wid = (blockIdx.x * 256 + threadIdx.x) >> 6;
    int quad = lane >> 4, l15 = lane & 15;
    int nbase = wid * 64;
    if (nbase >= N) return;

    f16x8 Bu[8], Bm[8], Bw[8];
#pragma unroll
    for (int i = 0; i < 8; ++i) {
        Bu[i] = Bfrag[i * 64 + lane];
        Bm[i] = Bfrag[(8 + i) * 64 + lane];
        Bw[i] = Bfrag[(16 + i) * 64 + lane];
    }
    float mbuv[4], b1v[4], b2v[4];
#pragma unroll
    for (int nt = 0; nt < 4; ++nt) {
        mbuv[nt] = mbu[nt * 16 + l15];
        b1v[nt] = ub1[nt * 16 + l15];
        b2v[nt] = ub2[nt * 16 + l15];
    }

    for (int mt = 0; mt < 4; ++mt) {
        int na = nbase + mt * 16 + l15;
        if (na >= N) na = N - 1;
        const f16x8* xrow = (const f16x8*)(xh + (size_t)na * H);
        f16x8 Ax[2];
        Ax[0] = xrow[quad];
        Ax[1] = xrow[4 + quad];
        const f16x8* arow = (const f16x8*)(agg + (size_t)na * H);
        f16x8 Aa[2];
        Aa[0] = arow[quad];
        Aa[1] = arow[4 + quad];

        f32x4 Cx[4], Ca[4];
#pragma unroll
        for (int nt = 0; nt < 4; ++nt) {
            f32x4 cx = {0.f, 0.f, 0.f, 0.f}, ca = {0.f, 0.f, 0.f, 0.f};
#pragma unroll
            for (int kk = 0; kk < 2; ++kk) {
                cx = __builtin_amdgcn_mfma_f32_16x16x32_f16(Ax[kk], Bu[nt * 2 + kk], cx, 0, 0, 0);
                ca = __builtin_amdgcn_mfma_f32_16x16x32_f16(Aa[kk], Bm[nt * 2 + kk], ca, 0, 0, 0);
            }
            Cx[nt] = cx; Ca[nt] = ca;
        }

        int noder = nbase + mt * 16 + quad * 4;
        float sn_r[4];
#pragma unroll
        for (int r = 0; r < 4; ++r) {
            int ng = noder + r; if (ng >= N) ng = N - 1;
            sn_r[r] = snorm[ng];
        }

#pragma unroll
        for (int nt = 0; nt < 4; ++nt) {
#pragma unroll
            for (int r = 0; r < 4; ++r) {
                float hv = fmaxf(Cx[nt][r] + Ca[nt][r]
                                 + sn_r[r] * mbuv[nt] + b1v[nt], 0.f);
                hlds[wib][(quad * 4 + r) * 80 + nt * 16 + l15] = (_Float16)hv;
            }
        }
        __asm__ __volatile__("s_waitcnt lgkmcnt(0)" ::: "memory");
        f16x8 Ah[2];
        Ah[0] = *(const f16x8*)&hlds[wib][l15 * 80 + quad * 8];
        Ah[1] = *(const f16x8*)&hlds[wib][l15 * 80 + 32 + quad * 8];
        __asm__ __volatile__("s_waitcnt lgkmcnt(0)" ::: "memory");

        f32x4 C2[4];
#pragma unroll
        for (int nt = 0; nt < 4; ++nt) {
            f32x4 cc = {0.f, 0.f, 0.f, 0.f};
#pragma unroll
            for (int kk = 0; kk < 2; ++kk)
                cc = __builtin_amdgcn_mfma_f32_16x16x32_f16(Ah[kk], Bw[nt * 2 + kk], cc, 0, 0, 0);
            C2[nt] = cc;
        }

#pragma unroll
        for (int r = 0; r < 4; ++r) {
            int ng = noder + r;
            if (ng < N) {
#pragma unroll
                for (int nt = 0; nt < 4; ++nt) {
                    size_t idx = (size_t)ng * H + nt * 16 + l15;
                    float xo = (float)xh[idx];
                    xh[idx] = (_Float16)fmaxf(C2[nt][r] + b2v[nt] + xo, 0.f);
                }
            }
        }
    }
}

// ----------------------------------------------------------------- head ----
__global__ __launch_bounds__(256) void max_kernel(
    const _Float16* __restrict__ xh16, unsigned int* __restrict__ serp, int N)
{
    int j = threadIdx.x & (H - 1);
    int g = (blockIdx.x * 256 + threadIdx.x) >> 6;
    int stride = (gridDim.x * 256) >> 6;
    float m = 0.f;  // x >= 0 after relu
    for (int n = g; n < N; n += stride)
        m = fmaxf(m, (float)xh16[(size_t)n * H + j]);
    atomicMax(serp + j, __float_as_uint(m));
}

__global__ void head_kernel(const unsigned int* __restrict__ serp,
                            const float* __restrict__ hW,
                            const float* __restrict__ hb,
                            float* __restrict__ out)
{
    int j = threadIdx.x;  // 64 threads = 1 wave
    float v = __uint_as_float(serp[j]) * hW[j];
#pragma unroll
    for (int off = 32; off > 0; off >>= 1) v += __shfl_down(v, off);
    if (j == 0) out[0] = v + hb[0];
}

// --------------------------------------------------------------- launch ----
extern "C" void kernel_launch(void* const* d_in, const int* in_sizes, int n_in,
                              void* d_out, int out_size, void* d_ws, size_t ws_size,
                              hipStream_t stream)
{
    const float* nf  = (const float*)d_in[0];
    const int*   ei  = (const int*)d_in[1];
    const float* ew  = (const float*)d_in[2];
    const float* eW  = (const float*)d_in[3];
    const float* eb_ = (const float*)d_in[4];
    const float* mW1 = (const float*)d_in[5];
    const float* mb1 = (const float*)d_in[6];
    const float* mW2 = (const float*)d_in[7];
    const float* mb2 = (const float*)d_in[8];
    const float* aW1 = (const float*)d_in[9];
    const float* ab1 = (const float*)d_in[10];
    const float* aW2 = (const float*)d_in[11];
    const float* ab2 = (const float*)d_in[12];
    const float* uW1 = (const float*)d_in[13];
    const float* ub1 = (const float*)d_in[14];
    const float* uW2 = (const float*)d_in[15];
    const float* ub2 = (const float*)d_in[16];
    const float* hW  = (const float*)d_in[17];
    const float* hb  = (const float*)d_in[18];

    int N = in_sizes[0] / F;
    int E = in_sizes[2];
    const int* row = ei;
    const int* col = ei + E;

    size_t Nr = ((size_t)N + 3) & ~(size_t)3;
    size_t Er = ((size_t)E + 3) & ~(size_t)3;
    int NBK = (N + BSC - 1) / BSC;         // buckets (= fused-kernel grid)
    int NB  = (E + EPB - 1) / EPB;         // blocks in count/place passes
    size_t M = (size_t)NBK * NB;           // bucket-count array size
    size_t Mr = (M + 3) & ~(size_t)3;

    _Float16* xh   = (_Float16*)d_ws;                 // Nr*64 f16
    _Float16* aggN = xh + Nr * 64;                    // Nr*64 f16 (normalized)
    float* snorm   = (float*)(aggN + Nr * 64);        // Nr
    unsigned int* serp = (unsigned int*)(snorm + Nr); // 64
    int* bsum      = (int*)(serp + 64);               // 256
    f16x8* msgB    = (f16x8*)(bsum + 256);            // 2048 units
    f16x8* attB    = msgB + 2048;                     // 1024 units
    float* M2U     = (float*)(attB + 1024);           // 8192
    float* mbu     = M2U + 8192;                      // 128
    f16x8* updB    = (f16x8*)(mbu + 128);             // 3072 units
    int* cnt       = (int*)(updB + 3072);             // Mr
    int* off       = cnt + Mr;                        // Mr
    int4* edata    = (int4*)(off + Mr);               // Er int4

    int nb_n = (N + 255) / 256;
    int nb_scanM = (int)((M + 1023) / 1024);          // <=256 (M<=262144)

    count_bucket_kernel<<<NB, 256, 0, stream>>>(col, cnt, E, NB, NBK);
    scan1_kernel<<<nb_scanM, 256, 0, stream>>>(cnt, off, bsum, (int)M);
    scan2_kernel<<<1, 256, 0, stream>>>(bsum, nb_scanM);
    scan3_kernel<<<(int)((M + 255) / 256), 256, 0, stream>>>(off, bsum, (int)M);
    place_kernel<<<NB, 256, 0, stream>>>(row, col, ew, off, edata, E, NB, NBK);

    packfrag_kernel<<<12, 256, 0, stream>>>(mW1, aW1, msgB, attB);
    prep_update_kernel<<<32, 256, 0, stream>>>(mW2, mb2, uW1, M2U, mbu);
    packfrag_upd_kernel<<<12, 256, 0, stream>>>(uW1, M2U, uW2, updB);
    embed_kernel<<<nb_n, 256, 0, stream>>>(nf, eW, eb_, xh, N);

    int nwaves_n = (N + 63) / 64;
    for (int l = 0; l < 2; ++l) {
        edge_fused_kernel<<<NBK, 256, 0, stream>>>(
            xh, edata, off,
            msgB + (size_t)l * 16 * 64,
            attB + (size_t)l * 8 * 64,
            mb1 + (size_t)l * H,
            ab1 + (size_t)l * (H / 2),
            aW2 + (size_t)l * (H / 2), ab2 + (size_t)l,
            aggN, snorm, N, E, NB, NBK);
        update_mfma_kernel<<<(nwaves_n + 3) / 4, 256, 0, stream>>>(
            xh, aggN, snorm,
            updB + (size_t)l * 24 * 64,
            mbu + (size_t)l * 64,
            ub1 + (size_t)l * H, ub2 + (size_t)l * H, N);
    }

    hipMemsetAsync(serp, 0, 64 * sizeof(unsigned int), stream);
    max_kernel<<<256, 256, 0, stream>>>(xh, serp, N);
    head_kernel<<<1, 64, 0, stream>>>(serp, hW, hb, (float*)d_out);
}

// Round 4
// 1093.646 us; speedup vs baseline: 1.4703x; 1.4696x over previous
//
#include <hip/hip_runtime.h>
#include <hip/hip_bf16.h>
#include <math.h>

#define H 64
#define F 18
#define BSC 32        // destination nodes per bucket (per-wave LDS replicas)
#define NBK_MAX 3456  // max buckets supported by count/place LDS histograms
#define EPB 8192      // edges per block in count/place passes

typedef _Float16 f16x8 __attribute__((ext_vector_type(8)));
typedef float f32x4 __attribute__((ext_vector_type(4)));

// ---------------------------------------------------------------- embed ----
__global__ __launch_bounds__(256) void embed_kernel(
    const float* __restrict__ nf, const float* __restrict__ W,
    const float* __restrict__ b, _Float16* __restrict__ xh, int N)
{
    int n = blockIdx.x * 256 + threadIdx.x;
    if (n >= N) return;
    float acc[H];
#pragma unroll
    for (int j = 0; j < H; ++j) acc[j] = b[j];
    const float* f = nf + (long)n * F;
#pragma unroll
    for (int i = 0; i < F; ++i) {
        float c = f[i];
        const float* w = W + i * H;
#pragma unroll
        for (int j = 0; j < H; ++j) acc[j] += c * w[j];
    }
    union { uint4 v[8]; _Float16 h[64]; } O;
#pragma unroll
    for (int j = 0; j < H; ++j) O.h[j] = (_Float16)fmaxf(acc[j], 0.f);
    uint4* xo = (uint4*)(xh + (size_t)n * H);
#pragma unroll
    for (int i = 0; i < 8; ++i) xo[i] = O.v[i];
}

// ------------------------------------------------- B-fragment prepack -----
__global__ __launch_bounds__(256) void packfrag_kernel(
    const float* __restrict__ mW1, const float* __restrict__ aW1,
    f16x8* __restrict__ msgB, f16x8* __restrict__ attB)
{
    int t = blockIdx.x * 256 + threadIdx.x;  // 0..3071
    if (t >= 3072) return;
    int lane = t & 63;
    int frag = t >> 6;            // 0..47
    int l = frag / 24, f = frag % 24;
    int quad = lane >> 4, l15 = lane & 15;
    f16x8 v;
    if (f < 16) {
        int nt = f >> 2, kk = f & 3;
        const float* W = mW1 + (size_t)l * 128 * 64;
#pragma unroll
        for (int j = 0; j < 8; ++j) {
            int k = kk * 32 + quad * 8 + j;
            v[j] = (_Float16)W[k * 64 + nt * 16 + l15];
        }
        msgB[((size_t)l * 16 + f) * 64 + lane] = v;
    } else {
        int f2 = f - 16;
        int nt = f2 >> 2, kk = f2 & 3;
        const float* W = aW1 + (size_t)l * 128 * 32;
#pragma unroll
        for (int j = 0; j < 8; ++j) {
            int k = kk * 32 + quad * 8 + j;
            v[j] = (_Float16)W[k * 32 + nt * 16 + l15];
        }
        attB[((size_t)l * 8 + f2) * 64 + lane] = v;
    }
}

// ---------------------------------------------- update-path precompute ----
__global__ __launch_bounds__(256) void prep_update_kernel(
    const float* __restrict__ mW2, const float* __restrict__ mb2,
    const float* __restrict__ uW1,
    float* __restrict__ M2U, float* __restrict__ mbu)
{
    int t = blockIdx.x * 256 + threadIdx.x;  // 0..8191
    if (t >= 2 * 64 * 64) return;
    int l = t >> 12, r = t & 4095;
    int i = r >> 6, j = r & 63;
    const float* W2 = mW2 + (size_t)l * 4096;
    const float* U1b = uW1 + (size_t)l * 8192 + 4096;  // rows 64..127
    float s = 0.f;
    for (int k = 0; k < 64; ++k) s += W2[i * 64 + k] * U1b[k * 64 + j];
    M2U[t] = s;
    if (i == 0) {
        float sb = 0.f;
        const float* b2 = mb2 + (size_t)l * 64;
        for (int k = 0; k < 64; ++k) sb += b2[k] * U1b[k * 64 + j];
        mbu[l * 64 + j] = sb;
    }
}

// aggN stored in TRUE feature order; g==1 not row-permuted.
__global__ __launch_bounds__(256) void packfrag_upd_kernel(
    const float* __restrict__ uW1, const float* __restrict__ M2U,
    const float* __restrict__ uW2, f16x8* __restrict__ updB)
{
    int t = blockIdx.x * 256 + threadIdx.x;  // 0..3071
    if (t >= 3072) return;
    int lane = t & 63;
    int frag = t >> 6;  // 0..47
    int l = frag / 24, f = frag % 24;
    int quad = lane >> 4, l15 = lane & 15;
    int g = f >> 3, ff = f & 7;
    int nt = ff >> 1, kk = ff & 1;
    const float* src;
    if (g == 0)      src = uW1 + (size_t)l * 8192;       // rows 0..63
    else if (g == 1) src = M2U + (size_t)l * 4096;
    else             src = uW2 + (size_t)l * 4096;
    f16x8 v;
#pragma unroll
    for (int j = 0; j < 8; ++j) {
        int k = kk * 32 + quad * 8 + j;
        v[j] = (_Float16)src[k * 64 + nt * 16 + l15];
    }
    updB[(size_t)frag * 64 + lane] = v;
}

// ----------------------------------------------- scan (2-level chain) -----
__global__ __launch_bounds__(256) void scan1_kernel(
    const int* __restrict__ deg, int* __restrict__ part,
    int* __restrict__ bsum, int N)
{
    __shared__ int lds[256];
    int t = threadIdx.x;
    int base = blockIdx.x * 1024 + t * 4;
    int v[4];
#pragma unroll
    for (int s = 0; s < 4; ++s) v[s] = (base + s < N) ? deg[base + s] : 0;
    int sum = v[0] + v[1] + v[2] + v[3];
    lds[t] = sum;
    __syncthreads();
    for (int off = 1; off < 256; off <<= 1) {
        int xv = (t >= off) ? lds[t - off] : 0;
        __syncthreads();
        lds[t] += xv;
        __syncthreads();
    }
    int excl = lds[t] - sum;
    if (t == 255) bsum[blockIdx.x] = lds[255];
    int p = excl;
#pragma unroll
    for (int s = 0; s < 4; ++s) {
        if (base + s < N) part[base + s] = p;
        p += v[s];
    }
}

__global__ __launch_bounds__(256) void scan3_kernel(
    int* __restrict__ part, const int* __restrict__ bsum, int N)
{
    int i = blockIdx.x * 256 + threadIdx.x;
    if (i >= N) return;
    part[i] = part[i] + bsum[i >> 10];
}

// ----------------------------------------- coarse bucket partition --------
__global__ __launch_bounds__(256) void count_bucket_kernel(
    const int* __restrict__ col, int* __restrict__ cnt,
    int E, int NB, int NBK)
{
    __shared__ int lc[NBK_MAX];
    int t = threadIdx.x;
    for (int i = t; i < NBK; i += 256) lc[i] = 0;
    __syncthreads();
    for (int s = 0; s < EPB / 256; ++s) {
        int e = blockIdx.x * EPB + s * 256 + t;
        if (e < E) atomicAdd(lc + (unsigned)col[e] / BSC, 1);
    }
    __syncthreads();
    for (int i = t; i < NBK; i += 256)
        cnt[(size_t)i * NB + blockIdx.x] = lc[i];
}

__global__ __launch_bounds__(256) void place_kernel(
    const int* __restrict__ row, const int* __restrict__ col,
    const float* __restrict__ ew, const int* __restrict__ off,
    int4* __restrict__ edata, int E, int NB, int NBK)
{
    __shared__ int lc[NBK_MAX];
    int t = threadIdx.x;
    for (int i = t; i < NBK; i += 256) lc[i] = 0;
    __syncthreads();
    for (int s = 0; s < EPB / 256; ++s) {
        int e = blockIdx.x * EPB + s * 256 + t;
        if (e < E) {
            int cv = col[e];
            int c = (unsigned)cv / BSC;
            int r = atomicAdd(lc + c, 1);
            int pos = off[(size_t)c * NB + blockIdx.x] + r;
            edata[pos] = make_int4(row[e], cv, __float_as_int(ew[e]), 0);
        }
    }
}

// ---------------------------------------------------------- fused edge ----
// R19b: NO f32 atomics (R17/R18 post-mortem: LDS f32 atomic RMW throughput
// ~250cy/wave64 fully serialized the CU: 98 tiles x 68 atomics x 250cy
// = 1.67M cy == the observed 703us). Instead: BSC=32 and per-WAVE private
// LDS accumulator replicas -> plain ds_read/add/ds_write at normal LDS
// rates. Within-instruction same-address collisions are eliminated by
// a one-edge-per-instruction epilogue: 64 lanes cover the edge's 64
// features (addr = nl*64+lane -> 2-way banks, free); values routed via
// f16-pair packing (cvt_pkrtz; f16 >= bf16 precision proven by R16's hfw)
// + 2 shuffles/edge + quad select. Cross-instruction same-node RMWs are
// correct by per-wave in-order LDS. Norm (sum fw) uses uniform cross-quad
// dedup (3 shfl_xor + predicated plain RMW). Finalize sums 4 replicas.
__global__ __launch_bounds__(256) void edge_fused_kernel(
    const _Float16* __restrict__ xh,
    const int4* __restrict__ edata, const int* __restrict__ off,
    const f16x8* __restrict__ msgB,  // [16][64] this layer
    const f16x8* __restrict__ attB,  // [8][64]
    const float* __restrict__ b1, const float* __restrict__ ab1,
    const float* __restrict__ aW2, const float* __restrict__ ab2,
    _Float16* __restrict__ aggN, float* __restrict__ snorm,
    int N, int E, int NB, int NBK)
{
    __shared__ float acc[4][BSC][H];   // per-wave replicas
    __shared__ float fwa[4][BSC];
    int tid = threadIdx.x;
    int b = blockIdx.x;
    for (int i = tid; i < 4 * BSC * H / 4; i += 256)
        ((float4*)acc)[i] = make_float4(0.f, 0.f, 0.f, 0.f);
    for (int i = tid; i < 4 * BSC; i += 256) ((float*)fwa)[i] = 0.f;

    int base = off[(size_t)b * NB];
    int end  = (b + 1 < NBK) ? off[(size_t)(b + 1) * NB] : E;
    int ecnt = end - base;
    int nlo  = b * BSC;

    int wib = tid >> 6;
    int lane = tid & 63;
    int quad = lane >> 4, l15 = lane & 15;
    float* accw = &acc[wib][0][0];
    float* fwaw = &fwa[wib][0];

    f16x8 mb[4][4], ab[2][4];
#pragma unroll
    for (int nt = 0; nt < 4; ++nt)
#pragma unroll
        for (int kk = 0; kk < 4; ++kk)
            mb[nt][kk] = msgB[(nt * 4 + kk) * 64 + lane];
#pragma unroll
    for (int nt = 0; nt < 2; ++nt)
#pragma unroll
        for (int kk = 0; kk < 4; ++kk)
            ab[nt][kk] = attB[(nt * 4 + kk) * 64 + lane];

    float ab1v0 = ab1[l15], ab1v1 = ab1[16 + l15];
    float aw20 = aW2[l15], aw21 = aW2[16 + l15];
    float ab2v = ab2[0];
    float bm[4];
#pragma unroll
    for (int nt = 0; nt < 4; ++nt) bm[nt] = b1[nt * 16 + l15];

    int jsw = ((l15 & 3) << 2) | (l15 >> 2);   // 4x4 transpose of l15
    __syncthreads();   // LDS zero done before any accumulation

    int ntiles = (ecnt + 63) >> 6;

    // prefetch first tile's edata
    int4 edmy;
    if (wib < ntiles) {
        int eown = (wib << 6) + lane;
        edmy = edata[base + (eown < ecnt ? eown : ecnt - 1)];
    }

    for (int t = wib; t < ntiles; t += 4) {
        int wbase = t << 6;

        // ---- issue NEXT tile's edata load (hidden under this tile) ----
        int4 ednx;
        int tn = t + 4;
        if (tn < ntiles) {
            int eo = (tn << 6) + lane;
            ednx = edata[base + (eo < ecnt ? eo : ecnt - 1)];
        }

        // ---- prologue: load A for sub-tile 0 ----
        f16x8 Acur[4], Anxt[4];
        {
            int sA = jsw;
            int rowv = __shfl(edmy.x, sA);
            int colv = __shfl(edmy.y, sA);
            const f16x8* rowp = (const f16x8*)(xh + (size_t)rowv * H);
            const f16x8* colp = (const f16x8*)(xh + (size_t)colv * H);
            Acur[0] = rowp[quad];
            Acur[1] = rowp[4 + quad];
            Acur[2] = colp[quad];
            Acur[3] = colp[4 + quad];
        }

#pragma unroll
        for (int mt = 0; mt < 4; ++mt) {
            // ---- issue next sub-tile's loads first (overlap) ----
            if (mt < 3) {
                int sA = (mt + 1) * 16 + jsw;
                int rowv = __shfl(edmy.x, sA);
                int colv = __shfl(edmy.y, sA);
                const f16x8* rowp = (const f16x8*)(xh + (size_t)rowv * H);
                const f16x8* colp = (const f16x8*)(xh + (size_t)colv * H);
                Anxt[0] = rowp[quad];
                Anxt[1] = rowp[4 + quad];
                Anxt[2] = colp[quad];
                Anxt[3] = colp[4 + quad];
            }

            // ---- attention GEMM (bias in C-init) ----
            f32x4 ac0 = {ab1v0, ab1v0, ab1v0, ab1v0};
            f32x4 ac1 = {ab1v1, ab1v1, ab1v1, ab1v1};
#pragma unroll
            for (int kk = 0; kk < 4; ++kk) {
                ac0 = __builtin_amdgcn_mfma_f32_16x16x32_f16(Acur[kk], ab[0][kk], ac0, 0, 0, 0);
                ac1 = __builtin_amdgcn_mfma_f32_16x16x32_f16(Acur[kk], ab[1][kk], ac1, 0, 0, 0);
            }
            float p[4];
#pragma unroll
            for (int r = 0; r < 4; ++r)
                p[r] = fmaxf(ac0[r], 0.f) * aw20 + fmaxf(ac1[r], 0.f) * aw21;
#pragma unroll
            for (int o = 1; o < 16; o <<= 1) {
#pragma unroll
                for (int r = 0; r < 4; ++r) p[r] += __shfl_xor(p[r], o);
            }
            float fw[4];
#pragma unroll
            for (int r = 0; r < 4; ++r) {
                int sl = mt * 16 + r * 4 + quad;
                float ewv = (wbase + sl < ecnt)
                            ? __int_as_float(__shfl(edmy.z, sl)) : 0.f;
                fw[r] = ewv / (1.f + __expf(-(p[r] + ab2v)));
            }

            // ---- message GEMM (bias in C-init) ----
            f32x4 mc[4];
#pragma unroll
            for (int nt = 0; nt < 4; ++nt) {
                f32x4 cc = {bm[nt], bm[nt], bm[nt], bm[nt]};
#pragma unroll
                for (int kk = 0; kk < 4; ++kk)
                    cc = __builtin_amdgcn_mfma_f32_16x16x32_f16(Acur[kk], mb[nt][kk], cc, 0, 0, 0);
                mc[nt] = cc;
            }

            // ---- epilogue: atomic-free per-edge LDS accumulate ----
#pragma unroll
            for (int r = 0; r < 4; ++r) {
                int sl0 = mt * 16 + r * 4;
                int nl0 = __shfl(edmy.y, sl0 + 0) - nlo;
                int nl1 = __shfl(edmy.y, sl0 + 1) - nlo;
                int nl2 = __shfl(edmy.y, sl0 + 2) - nlo;
                int nl3 = __shfl(edmy.y, sl0 + 3) - nlo;

                // own-quad edge's message, scaled (invalid edges have fw=0)
                float mm0 = fmaxf(mc[0][r], 0.f) * fw[r];
                float mm1 = fmaxf(mc[1][r], 0.f) * fw[r];
                float mm2 = fmaxf(mc[2][r], 0.f) * fw[r];
                float mm3 = fmaxf(mc[3][r], 0.f) * fw[r];
                auto a01 = __builtin_amdgcn_cvt_pkrtz(mm0, mm1);
                auto a23 = __builtin_amdgcn_cvt_pkrtz(mm2, mm3);
                int pk01, pk23;
                __builtin_memcpy(&pk01, &a01, 4);
                __builtin_memcpy(&pk23, &a23, 4);

                int shn = (quad & 1) * 16;
#pragma unroll
                for (int j = 0; j < 4; ++j) {
                    int s01 = __shfl(pk01, j * 16 + l15);
                    int s23 = __shfl(pk23, j * 16 + l15);
                    int sv = (quad < 2) ? s01 : s23;
                    union { unsigned short u; _Float16 h; } C;
                    C.u = (unsigned short)(((unsigned)sv) >> shn);
                    float v = (float)C.h;
                    int nlj = (j == 0) ? nl0 : (j == 1) ? nl1
                            : (j == 2) ? nl2 : nl3;
                    accw[nlj * H + lane] += v;   // plain LDS RMW, in-order
                }

                // ---- norm (sum fw): uniform cross-quad dedup, no atomics
                bool e10 = nl1 == nl0, e20 = nl2 == nl0, e21 = nl2 == nl1;
                bool e30 = nl3 == nl0, e31 = nl3 == nl1, e32 = nl3 == nl2;
                float fx1 = __shfl_xor(fw[r], 16);
                float fx2 = __shfl_xor(fw[r], 32);
                float fx3 = __shfl_xor(fw[r], 48);
                float fv = fw[r];
                bool alive;
                int nlw;
                if (quad == 0) {
                    fv += (e10 ? fx1 : 0.f) + (e20 ? fx2 : 0.f) + (e30 ? fx3 : 0.f);
                    alive = true; nlw = nl0;
                } else if (quad == 1) {
                    fv += (e21 ? fx3 : 0.f) + (e31 ? fx2 : 0.f);
                    alive = !e10; nlw = nl1;
                } else if (quad == 2) {
                    fv += (e32 ? fx1 : 0.f);
                    alive = !e20 && !e21; nlw = nl2;
                } else {
                    alive = !e30 && !e31 && !e32; nlw = nl3;
                }
                if (l15 == 0 && alive) fwaw[nlw] += fv;
            }

            if (mt < 3) {
#pragma unroll
                for (int i = 0; i < 4; ++i) Acur[i] = Anxt[i];
            }
        }

        if (tn < ntiles) edmy = ednx;
    }

    __syncthreads();
    // ---- finalize: reduce replicas, normalize, write aggN + snorm ----
    int nmax = N - nlo; if (nmax > BSC) nmax = BSC;
    for (int i = wib; i < nmax; i += 4) {
        float s = acc[0][i][lane] + acc[1][i][lane]
                + acc[2][i][lane] + acc[3][i][lane];
        float fws = fwa[0][i] + fwa[1][i] + fwa[2][i] + fwa[3][i];
        float inv = 1.f / fmaxf(fws, 1e-6f);
        aggN[(size_t)(nlo + i) * H + lane] = (_Float16)(s * inv);
        if (lane == 0) snorm[nlo + i] = fws * inv;
    }
}

// --------------------------------------------------------------- update ----
__global__ __launch_bounds__(256, 2) void update_mfma_kernel(
    _Float16* __restrict__ xh, const _Float16* __restrict__ agg,
    const float* __restrict__ snorm,
    const f16x8* __restrict__ Bfrag,  // [24][64] this layer
    const float* __restrict__ mbu,    // [64]
    const float* __restrict__ ub1, const float* __restrict__ ub2, int N)
{
    __shared__ __align__(16) _Float16 hlds[4][16 * 80];
    int wib = threadIdx.x >> 6;
    int lane = threadIdx.x & 63;
    int wid = (blockIdx.x * 256 + threadIdx.x) >> 6;
    int quad = lane >> 4, l15 = lane & 15;
    int nbase = wid * 64;
    if (nbase >= N) return;

    f16x8 Bu[8], Bm[8], Bw[8];
#pragma unroll
    for (int i = 0; i < 8; ++i) {
        Bu[i] = Bfrag[i * 64 + lane];
        Bm[i] = Bfrag[(8 + i) * 64 + lane];
        Bw[i] = Bfrag[(16 + i) * 64 + lane];
    }
    float mbuv[4], b1v[4], b2v[4];
#pragma unroll
    for (int nt = 0; nt < 4; ++nt) {
        mbuv[nt] = mbu[nt * 16 + l15];
        b1v[nt] = ub1[nt * 16 + l15];
        b2v[nt] = ub2[nt * 16 + l15];
    }

    for (int mt = 0; mt < 4; ++mt) {
        int na = nbase + mt * 16 + l15;
        if (na >= N) na = N - 1;
        const f16x8* xrow = (const f16x8*)(xh + (size_t)na * H);
        f16x8 Ax[2];
        Ax[0] = xrow[quad];
        Ax[1] = xrow[4 + quad];
        const f16x8* arow = (const f16x8*)(agg + (size_t)na * H);
        f16x8 Aa[2];
        Aa[0] = arow[quad];
        Aa[1] = arow[4 + quad];

        f32x4 Cx[4], Ca[4];
#pragma unroll
        for (int nt = 0; nt < 4; ++nt) {
            f32x4 cx = {0.f, 0.f, 0.f, 0.f}, ca = {0.f, 0.f, 0.f, 0.f};
#pragma unroll
            for (int kk = 0; kk < 2; ++kk) {
                cx = __builtin_amdgcn_mfma_f32_16x16x32_f16(Ax[kk], Bu[nt * 2 + kk], cx, 0, 0, 0);
                ca = __builtin_amdgcn_mfma_f32_16x16x32_f16(Aa[kk], Bm[nt * 2 + kk], ca, 0, 0, 0);
            }
            Cx[nt] = cx; Ca[nt] = ca;
        }

        int noder = nbase + mt * 16 + quad * 4;
        float sn_r[4];
#pragma unroll
        for (int r = 0; r < 4; ++r) {
            int ng = noder + r; if (ng >= N) ng = N - 1;
            sn_r[r] = snorm[ng];
        }

#pragma unroll
        for (int nt = 0; nt < 4; ++nt) {
#pragma unroll
            for (int r = 0; r < 4; ++r) {
                float hv = fmaxf(Cx[nt][r] + Ca[nt][r]
                                 + sn_r[r] * mbuv[nt] + b1v[nt], 0.f);
                hlds[wib][(quad * 4 + r) * 80 + nt * 16 + l15] = (_Float16)hv;
            }
        }
        __asm__ __volatile__("s_waitcnt lgkmcnt(0)" ::: "memory");
        f16x8 Ah[2];
        Ah[0] = *(const f16x8*)&hlds[wib][l15 * 80 + quad * 8];
        Ah[1] = *(const f16x8*)&hlds[wib][l15 * 80 + 32 + quad * 8];
        __asm__ __volatile__("s_waitcnt lgkmcnt(0)" ::: "memory");

        f32x4 C2[4];
#pragma unroll
        for (int nt = 0; nt < 4; ++nt) {
            f32x4 cc = {0.f, 0.f, 0.f, 0.f};
#pragma unroll
            for (int kk = 0; kk < 2; ++kk)
                cc = __builtin_amdgcn_mfma_f32_16x16x32_f16(Ah[kk], Bw[nt * 2 + kk], cc, 0, 0, 0);
            C2[nt] = cc;
        }

#pragma unroll
        for (int r = 0; r < 4; ++r) {
            int ng = noder + r;
            if (ng < N) {
#pragma unroll
                for (int nt = 0; nt < 4; ++nt) {
                    size_t idx = (size_t)ng * H + nt * 16 + l15;
                    float xo = (float)xh[idx];
                    xh[idx] = (_Float16)fmaxf(C2[nt][r] + b2v[nt] + xo, 0.f);
                }
            }
        }
    }
}

// ----------------------------------------------------------------- head ----
__global__ __launch_bounds__(256) void max_kernel(
    const _Float16* __restrict__ xh16, unsigned int* __restrict__ serp, int N)
{
    int j = threadIdx.x & (H - 1);
    int g = (blockIdx.x * 256 + threadIdx.x) >> 6;
    int stride = (gridDim.x * 256) >> 6;
    float m = 0.f;  // x >= 0 after relu
    for (int n = g; n < N; n += stride)
        m = fmaxf(m, (float)xh16[(size_t)n * H + j]);
    atomicMax(serp + j, __float_as_uint(m));
}

__global__ void head_kernel(const unsigned int* __restrict__ serp,
                            const float* __restrict__ hW,
                            const float* __restrict__ hb,
                            float* __restrict__ out)
{
    int j = threadIdx.x;  // 64 threads = 1 wave
    float v = __uint_as_float(serp[j]) * hW[j];
#pragma unroll
    for (int off = 32; off > 0; off >>= 1) v += __shfl_down(v, off);
    if (j == 0) out[0] = v + hb[0];
}

// --------------------------------------------------------------- launch ----
extern "C" void kernel_launch(void* const* d_in, const int* in_sizes, int n_in,
                              void* d_out, int out_size, void* d_ws, size_t ws_size,
                              hipStream_t stream)
{
    const float* nf  = (const float*)d_in[0];
    const int*   ei  = (const int*)d_in[1];
    const float* ew  = (const float*)d_in[2];
    const float* eW  = (const float*)d_in[3];
    const float* eb_ = (const float*)d_in[4];
    const float* mW1 = (const float*)d_in[5];
    const float* mb1 = (const float*)d_in[6];
    const float* mW2 = (const float*)d_in[7];
    const float* mb2 = (const float*)d_in[8];
    const float* aW1 = (const float*)d_in[9];
    const float* ab1 = (const float*)d_in[10];
    const float* aW2 = (const float*)d_in[11];
    const float* ab2 = (const float*)d_in[12];
    const float* uW1 = (const float*)d_in[13];
    const float* ub1 = (const float*)d_in[14];
    const float* uW2 = (const float*)d_in[15];
    const float* ub2 = (const float*)d_in[16];
    const float* hW  = (const float*)d_in[17];
    const float* hb  = (const float*)d_in[18];

    int N = in_sizes[0] / F;
    int E = in_sizes[2];
    const int* row = ei;
    const int* col = ei + E;

    size_t Nr = ((size_t)N + 3) & ~(size_t)3;
    size_t Er = ((size_t)E + 3) & ~(size_t)3;
    int NBK = (N + BSC - 1) / BSC;         // buckets (= fused-kernel grid)
    int NB  = (E + EPB - 1) / EPB;         // blocks in count/place passes
    size_t M = (size_t)NBK * NB;           // bucket-count array size
    size_t Mr = (M + 3) & ~(size_t)3;

    _Float16* xh   = (_Float16*)d_ws;                 // Nr*64 f16
    _Float16* aggN = xh + Nr * 64;                    // Nr*64 f16 (normalized)
    float* snorm   = (float*)(aggN + Nr * 64);        // Nr
    unsigned int* serp = (unsigned int*)(snorm + Nr); // 64
    int* bsumA     = (int*)(serp + 64);               // 1024
    int* bsumAs    = bsumA + 1024;                    // 1024
    int* bsumT     = bsumAs + 1024;                   // 4
    f16x8* msgB    = (f16x8*)(bsumT + 4);             // 2048 units
    f16x8* attB    = msgB + 2048;                     // 1024 units
    float* M2U     = (float*)(attB + 1024);           // 8192
    float* mbu     = M2U + 8192;                      // 128
    f16x8* updB    = (f16x8*)(mbu + 128);             // 3072 units
    int* cnt       = (int*)(updB + 3072);             // Mr
    int* off       = cnt + Mr;                        // Mr
    int4* edata    = (int4*)(off + Mr);               // Er int4

    int nb_n = (N + 255) / 256;
    int nbA = (int)((M + 1023) / 1024);               // level-A scan blocks (<=1024)

    count_bucket_kernel<<<NB, 256, 0, stream>>>(col, cnt, E, NB, NBK);
    scan1_kernel<<<nbA, 256, 0, stream>>>(cnt, off, bsumA, (int)M);
    scan1_kernel<<<1, 256, 0, stream>>>(bsumA, bsumAs, bsumT, nbA);
    scan3_kernel<<<(int)((M + 255) / 256), 256, 0, stream>>>(off, bsumAs, (int)M);
    place_kernel<<<NB, 256, 0, stream>>>(row, col, ew, off, edata, E, NB, NBK);

    packfrag_kernel<<<12, 256, 0, stream>>>(mW1, aW1, msgB, attB);
    prep_update_kernel<<<32, 256, 0, stream>>>(mW2, mb2, uW1, M2U, mbu);
    packfrag_upd_kernel<<<12, 256, 0, stream>>>(uW1, M2U, uW2, updB);
    embed_kernel<<<nb_n, 256, 0, stream>>>(nf, eW, eb_, xh, N);

    int nwaves_n = (N + 63) / 64;
    for (int l = 0; l < 2; ++l) {
        edge_fused_kernel<<<NBK, 256, 0, stream>>>(
            xh, edata, off,
            msgB + (size_t)l * 16 * 64,
            attB + (size_t)l * 8 * 64,
            mb1 + (size_t)l * H,
            ab1 + (size_t)l * (H / 2),
            aW2 + (size_t)l * (H / 2), ab2 + (size_t)l,
            aggN, snorm, N, E, NB, NBK);
        update_mfma_kernel<<<(nwaves_n + 3) / 4, 256, 0, stream>>>(
            xh, aggN, snorm,
            updB + (size_t)l * 24 * 64,
            mbu + (size_t)l * 64,
            ub1 + (size_t)l * H, ub2 + (size_t)l * H, N);
    }

    hipMemsetAsync(serp, 0, 64 * sizeof(unsigned int), stream);
    max_kernel<<<256, 256, 0, stream>>>(xh, serp, N);
    head_kernel<<<1, 64, 0, stream>>>(serp, hW, hb, (float*)d_out);
}